// Round 1
// baseline (1567.927 us; speedup 1.0000x reference)
//
#include <hip/hip_runtime.h>

#define B_   4
#define IC   64
#define OC   128
#define HH   128
#define WW   128
#define HP   130      // padded H/W
#define XOF  384      // x_off spatial (128*3)
#define OH2  382      // final output spatial
#define ICB  16       // ic chunk for conv2

// ---------------------------------------------------------------------------
// Kernel A: offset conv. x(4,64,128,128) * w_p(18,64,3,3) + b_p -> off(4,18,128,128)
// One thread per pixel, all 18 output channels. Weight indices are uniform
// across the wave -> scalar (s_load) path, no LDS needed.
// ---------------------------------------------------------------------------
__global__ __launch_bounds__(256) void offset_conv(const float* __restrict__ x,
                                                   const float* __restrict__ w_p,
                                                   const float* __restrict__ b_p,
                                                   float* __restrict__ off) {
    int t  = blockIdx.x * 256 + threadIdx.x;       // 4*128*128 = 65536 exact
    int px = t % WW;
    int py = (t / WW) % HH;
    int b  = t / (WW * HH);

    float acc[18];
#pragma unroll
    for (int co = 0; co < 18; ++co) acc[co] = b_p[co];

    const float* xb = x + (size_t)b * IC * HH * WW;
    for (int ci = 0; ci < IC; ++ci) {
        const float* xc = xb + (size_t)ci * HH * WW;
        float xv[9];
#pragma unroll
        for (int ky = 0; ky < 3; ++ky) {
            int yy = py + ky - 1;
            bool yok = (yy >= 0) && (yy < HH);
#pragma unroll
            for (int kx = 0; kx < 3; ++kx) {
                int xx = px + kx - 1;
                bool ok = yok && (xx >= 0) && (xx < WW);
                xv[ky * 3 + kx] = ok ? xc[yy * WW + xx] : 0.f;
            }
        }
#pragma unroll
        for (int co = 0; co < 18; ++co) {
            const float* wrow = w_p + ((size_t)co * IC + ci) * 9;
#pragma unroll
            for (int k = 0; k < 9; ++k)
                acc[co] = fmaf(wrow[k], xv[k], acc[co]);
        }
    }

    float* ob = off + (size_t)b * 18 * HH * WW + (size_t)py * WW + px;
#pragma unroll
    for (int co = 0; co < 18; ++co) ob[(size_t)co * HH * WW] = acc[co];
}

// ---------------------------------------------------------------------------
// Kernel B: bilinear sampling -> x_off[bl][c][yy][xx], yy=i*3+kh, xx=j*3+kw.
// One thread per x_off element; consecutive threads -> consecutive xx
// (coalesced stores). Follows reference clamp ordering exactly:
//   q_lt = clamp(floor(p_unclamped)); q_rb = clamp(floor(p)+1); p clamped after.
// ---------------------------------------------------------------------------
__global__ __launch_bounds__(256) void sample_kernel(const float* __restrict__ x,
                                                     const float* __restrict__ off,
                                                     float* __restrict__ xoff,
                                                     int b0, int nb) {
    size_t t = (size_t)blockIdx.x * 256 + threadIdx.x;   // nb*64*384*384 exact
    int xx = (int)(t % XOF);
    size_t t1 = t / XOF;
    int yy = (int)(t1 % XOF);
    size_t t2 = t1 / XOF;
    int c  = (int)(t2 % IC);
    int bl = (int)(t2 / IC);
    if (bl >= nb) return;
    int b = b0 + bl;

    int j = xx / 3, kw = xx % 3;
    int i = yy / 3, kh = yy % 3;
    int n = kh * 3 + kw;

    const float* offb = off + (size_t)b * 18 * HH * WW + (size_t)i * WW + j;
    float offr = offb[(size_t)n * HH * WW];
    float offc = offb[(size_t)(n + 9) * HH * WW];

    // p = p0 + pn + offset;  p0 = i+1, pn = kh-1  ->  i + kh + off
    float pr = (float)(i + kh) + offr;
    float pc = (float)(j + kw) + offc;

    float r0f = floorf(pr), c0f = floorf(pc);
    int r0 = min(max((int)r0f, 0), HP - 1);
    int c0 = min(max((int)c0f, 0), HP - 1);
    int r1 = min(max((int)(r0f + 1.f), 0), HP - 1);
    int c1 = min(max((int)(c0f + 1.f), 0), HP - 1);

    float prc = fminf(fmaxf(pr, 0.f), (float)(HP - 1));
    float pcc = fminf(fmaxf(pc, 0.f), (float)(HP - 1));

    float glt = (1.f + ((float)r0 - prc)) * (1.f + ((float)c0 - pcc));
    float grb = (1.f - ((float)r1 - prc)) * (1.f - ((float)c1 - pcc));
    float glb = (1.f + ((float)r0 - prc)) * (1.f - ((float)c1 - pcc));
    float grt = (1.f - ((float)r1 - prc)) * (1.f + ((float)c0 - pcc));

    const float* xc = x + ((size_t)b * IC + c) * HH * WW;

    // xp[r][cc] = x[r-1][cc-1] if in range else 0
    int rr0 = r0 - 1, cc0 = c0 - 1, rr1 = r1 - 1, cc1 = c1 - 1;
    bool r0ok = (rr0 >= 0) && (rr0 < HH);
    bool r1ok = (rr1 >= 0) && (rr1 < HH);
    bool c0ok = (cc0 >= 0) && (cc0 < WW);
    bool c1ok = (cc1 >= 0) && (cc1 < WW);
    float xlt = (r0ok && c0ok) ? xc[(size_t)rr0 * WW + cc0] : 0.f;
    float xrb = (r1ok && c1ok) ? xc[(size_t)rr1 * WW + cc1] : 0.f;
    float xlb = (r0ok && c1ok) ? xc[(size_t)rr0 * WW + cc1] : 0.f;
    float xrt = (r1ok && c0ok) ? xc[(size_t)rr1 * WW + cc0] : 0.f;

    float v = glt * xlt + grb * xrb + glb * xlb + grt * xrt;
    xoff[((size_t)bl * IC + c) * XOF * XOF + (size_t)yy * XOF + xx] = v;
}

// ---------------------------------------------------------------------------
// Kernel C: 3x3 stride-1 conv, x_off(64,384,384) -> out(128,382,382) per batch.
// Block = 256 threads: 16x16 spatial tile x 32 output channels.
// Thread = 2x2 pixels x 8 oc (32 fp32 accumulators). ic chunked by ICB=16.
// ---------------------------------------------------------------------------
__global__ __launch_bounds__(256) void conv2_kernel(const float* __restrict__ xoff,
                                                    const float* __restrict__ wc,
                                                    float* __restrict__ out,
                                                    int b0, int nb) {
    int tx0 = blockIdx.x * 16;
    int ty0 = blockIdx.y * 16;
    int zb  = blockIdx.z;          // nb*4
    int ocb = (zb & 3) * 32;
    int bl  = zb >> 2;
    int b   = b0 + bl;

    __shared__ float s_in[ICB][18][18];
    __shared__ float s_w[ICB][9][32];

    int tid  = threadIdx.x;
    int ocg  = tid >> 6;           // 0..3, wave-uniform
    int lane = tid & 63;
    int sx   = lane & 7;           // 0..7
    int sy   = lane >> 3;          // 0..7

    float acc[2][2][8];
#pragma unroll
    for (int a = 0; a < 2; ++a)
#pragma unroll
        for (int bq = 0; bq < 2; ++bq)
#pragma unroll
            for (int o = 0; o < 8; ++o) acc[a][bq][o] = 0.f;

    const float* xb = xoff + (size_t)bl * IC * XOF * XOF;

    for (int ic0 = 0; ic0 < IC; ic0 += ICB) {
        __syncthreads();   // protect previous chunk's LDS reads
        // stage input tile (ICB x 18 x 18)
        for (int idx = tid; idx < ICB * 18 * 18; idx += 256) {
            int col = idx % 18;
            int row = (idx / 18) % 18;
            int ic  = idx / (18 * 18);
            int gy = ty0 + row, gx = tx0 + col;
            float v = 0.f;
            if (gy < XOF && gx < XOF)
                v = xb[((size_t)(ic0 + ic)) * XOF * XOF + (size_t)gy * XOF + gx];
            s_in[ic][row][col] = v;
        }
        // stage weights (ICB x 9 x 32), layout oc-fastest for b128 reads
        for (int idx = tid; idx < ICB * 9 * 32; idx += 256) {
            int oo = idx % 32;
            int k  = (idx / 32) % 9;
            int ic = idx / (32 * 9);
            s_w[ic][k][oo] = wc[(((size_t)(ocb + oo) * IC) + (ic0 + ic)) * 9 + k];
        }
        __syncthreads();

#pragma unroll
        for (int ic = 0; ic < ICB; ++ic) {
            float iv[4][4];
#pragma unroll
            for (int r = 0; r < 4; ++r)
#pragma unroll
                for (int cc = 0; cc < 4; ++cc)
                    iv[r][cc] = s_in[ic][2 * sy + r][2 * sx + cc];
#pragma unroll
            for (int ky = 0; ky < 3; ++ky)
#pragma unroll
                for (int kx = 0; kx < 3; ++kx) {
                    float w8[8];
#pragma unroll
                    for (int o = 0; o < 8; ++o)
                        w8[o] = s_w[ic][ky * 3 + kx][ocg * 8 + o];
#pragma unroll
                    for (int py2 = 0; py2 < 2; ++py2)
#pragma unroll
                        for (int px2 = 0; px2 < 2; ++px2) {
                            float inv = iv[py2 + ky][px2 + kx];
#pragma unroll
                            for (int o = 0; o < 8; ++o)
                                acc[py2][px2][o] = fmaf(inv, w8[o], acc[py2][px2][o]);
                        }
                }
        }
    }

    // write out: out[b][ocb + ocg*8 + o][ty0+2sy+py2][tx0+2sx+px2]
#pragma unroll
    for (int py2 = 0; py2 < 2; ++py2) {
        int oy = ty0 + 2 * sy + py2;
        if (oy >= OH2) continue;
#pragma unroll
        for (int px2 = 0; px2 < 2; ++px2) {
            int ox = tx0 + 2 * sx + px2;
            if (ox >= OH2) continue;
#pragma unroll
            for (int o = 0; o < 8; ++o) {
                int oc = ocb + ocg * 8 + o;
                out[(((size_t)b * OC + oc) * OH2 + oy) * OH2 + ox] = acc[py2][px2][o];
            }
        }
    }
}

// ---------------------------------------------------------------------------
extern "C" void kernel_launch(void* const* d_in, const int* in_sizes, int n_in,
                              void* d_out, int out_size, void* d_ws, size_t ws_size,
                              hipStream_t stream) {
    const float* x      = (const float*)d_in[0];
    const float* w_p    = (const float*)d_in[1];
    const float* b_p    = (const float*)d_in[2];
    const float* w_conv = (const float*)d_in[3];
    float* out = (float*)d_out;

    const size_t offElems  = (size_t)B_ * 18 * HH * WW;          // 1,179,648
    const size_t xofElems  = (size_t)IC * XOF * XOF;             // per batch: 9,437,184
    const size_t offBytes  = offElems * 4;
    const size_t xofBytes  = xofElems * 4;

    float* off  = (float*)d_ws;
    float* xoff = off + offElems;

    // Kernel A: offsets for all 4 batches
    offset_conv<<<(B_ * HH * WW) / 256, 256, 0, stream>>>(x, w_p, b_p, off);

    const int tilesXY = (OH2 + 15) / 16;   // 24

    if (ws_size >= offBytes + 4 * xofBytes) {
        // all batches staged at once
        size_t total = 4 * xofElems;
        sample_kernel<<<(unsigned)(total / 256), 256, 0, stream>>>(x, off, xoff, 0, 4);
        dim3 grid(tilesXY, tilesXY, 4 * 4);
        conv2_kernel<<<grid, 256, 0, stream>>>(xoff, w_conv, out, 0, 4);
    } else {
        // per-batch staging (needs offBytes + xofBytes of ws)
        for (int b = 0; b < B_; ++b) {
            sample_kernel<<<(unsigned)(xofElems / 256), 256, 0, stream>>>(x, off, xoff, b, 1);
            dim3 grid(tilesXY, tilesXY, 4);
            conv2_kernel<<<grid, 256, 0, stream>>>(xoff, w_conv, out, b, 1);
        }
    }
}

// Round 2
// 395.940 us; speedup vs baseline: 3.9600x; 3.9600x over previous
//
#include <hip/hip_runtime.h>
#include <hip/hip_bf16.h>

#define B_   4
#define IC   64
#define OC   128
#define HH   128
#define WW   128
#define HP   130      // padded H/W for sampling
#define XOF  384      // x_off spatial (128*3)
#define XPAD 388      // padded x-dim of NHWC x_off (needs up to 385)
#define OH2  382      // final output spatial
#define KSTEPS 18     // 9 kernel positions * 2 ic-halves (K=32 each)

typedef __attribute__((ext_vector_type(4))) float f32x4;
typedef __attribute__((ext_vector_type(8))) __bf16 bf16x8;
typedef __attribute__((ext_vector_type(4), aligned(4))) float f32x4u;

__device__ __forceinline__ void gload16(const void* gsrc, void* ldst) {
    __builtin_amdgcn_global_load_lds(
        (const __attribute__((address_space(1))) void*)gsrc,
        (__attribute__((address_space(3))) void*)ldst, 16, 0, 0);
}

// ---------------------------------------------------------------------------
// Kernel A: offset conv (unchanged from R1, fp32).
// ---------------------------------------------------------------------------
__global__ __launch_bounds__(256) void offset_conv(const float* __restrict__ x,
                                                   const float* __restrict__ w_p,
                                                   const float* __restrict__ b_p,
                                                   float* __restrict__ off) {
    int t  = blockIdx.x * 256 + threadIdx.x;
    int px = t % WW;
    int py = (t / WW) % HH;
    int b  = t / (WW * HH);

    float acc[18];
#pragma unroll
    for (int co = 0; co < 18; ++co) acc[co] = b_p[co];

    const float* xb = x + (size_t)b * IC * HH * WW;
    for (int ci = 0; ci < IC; ++ci) {
        const float* xc = xb + (size_t)ci * HH * WW;
        float xv[9];
#pragma unroll
        for (int ky = 0; ky < 3; ++ky) {
            int yy = py + ky - 1;
            bool yok = (yy >= 0) && (yy < HH);
#pragma unroll
            for (int kx = 0; kx < 3; ++kx) {
                int xx = px + kx - 1;
                bool ok = yok && (xx >= 0) && (xx < WW);
                xv[ky * 3 + kx] = ok ? xc[yy * WW + xx] : 0.f;
            }
        }
#pragma unroll
        for (int co = 0; co < 18; ++co) {
            const float* wrow = w_p + ((size_t)co * IC + ci) * 9;
#pragma unroll
            for (int k = 0; k < 9; ++k)
                acc[co] = fmaf(wrow[k], xv[k], acc[co]);
        }
    }

    float* ob = off + (size_t)b * 18 * HH * WW + (size_t)py * WW + px;
#pragma unroll
    for (int co = 0; co < 18; ++co) ob[(size_t)co * HH * WW] = acc[co];
}

// ---------------------------------------------------------------------------
// Kernel P: pre-transpose weights to bf16 K-step tiles.
// Bt[s][kg][oc][e] = bf16( w_conv[oc][(s&1)*32 + kg*8 + e][ (s>>1)/3 ][ (s>>1)%3 ] )
// ---------------------------------------------------------------------------
__global__ __launch_bounds__(256) void prep_w(const float* __restrict__ wc,
                                              unsigned short* __restrict__ Bt) {
    int t = blockIdx.x * 256 + threadIdx.x;
    if (t >= KSTEPS * 4 * 128 * 8) return;
    int e  = t & 7;
    int oc = (t >> 3) & 127;
    int kg = (t >> 10) & 3;
    int s  = t >> 12;
    int ic = ((s & 1) << 5) + (kg << 3) + e;
    int kpos = s >> 1;
    int ky = kpos / 3, kx = kpos % 3;
    float v = wc[(((size_t)oc * IC + ic) * 3 + ky) * 3 + kx];
    __hip_bfloat16 h = __float2bfloat16(v);
    Bt[t] = reinterpret_cast<unsigned short&>(h);
}

// ---------------------------------------------------------------------------
// Kernel Z: zero the x-pad columns [384,388) of the NHWC x_off buffer.
// ---------------------------------------------------------------------------
__global__ __launch_bounds__(256) void pad_zero(unsigned short* __restrict__ xoff, int nb) {
    int t = blockIdx.x * 256 + threadIdx.x;      // nb*384*4*64 exact
    int c  = t & 63;
    int xp = (t >> 6) & 3;
    int yy = (t >> 8) % XOF;
    int bl = (t >> 8) / XOF;
    if (bl >= nb) return;
    xoff[(((size_t)bl * XOF + yy) * XPAD + XOF + xp) * IC + c] = 0;
}

// ---------------------------------------------------------------------------
// Kernel B: bilinear sampling -> bf16 NHWC x_off[bl][yy][xx][c].
// Block: one row yy, 64 xx, all 64 c. Phase 1 computes with xx-fastest lanes
// (coalesced x gathers), stages into LDS; phase 2 writes NHWC with c-fastest
// lanes (128 B contiguous per pixel). Sampling math identical to R1 (passed).
// ---------------------------------------------------------------------------
__global__ __launch_bounds__(256) void sample_nhwc(const float* __restrict__ x,
                                                   const float* __restrict__ off,
                                                   unsigned short* __restrict__ xoff,
                                                   int b0, int nb) {
    __shared__ unsigned short ls[64][68];

    int xx0 = blockIdx.x * 64;
    int yy  = blockIdx.y;
    int bl  = blockIdx.z;
    int b   = b0 + bl;

    int t  = threadIdx.x;
    int xl = t & 63;
    int cg = t >> 6;           // 0..3
    int xx = xx0 + xl;

    int j = xx / 3, kw = xx % 3;
    int i = yy / 3, kh = yy % 3;
    int n = kh * 3 + kw;

    const float* offb = off + (size_t)b * 18 * HH * WW + (size_t)i * WW + j;
    float offr = offb[(size_t)n * HH * WW];
    float offc = offb[(size_t)(n + 9) * HH * WW];

    float pr = (float)(i + kh) + offr;
    float pc = (float)(j + kw) + offc;

    float r0f = floorf(pr), c0f = floorf(pc);
    int r0 = min(max((int)r0f, 0), HP - 1);
    int c0 = min(max((int)c0f, 0), HP - 1);
    int r1 = min(max((int)(r0f + 1.f), 0), HP - 1);
    int c1 = min(max((int)(c0f + 1.f), 0), HP - 1);

    float prc = fminf(fmaxf(pr, 0.f), (float)(HP - 1));
    float pcc = fminf(fmaxf(pc, 0.f), (float)(HP - 1));

    float glt = (1.f + ((float)r0 - prc)) * (1.f + ((float)c0 - pcc));
    float grb = (1.f - ((float)r1 - prc)) * (1.f - ((float)c1 - pcc));
    float glb = (1.f + ((float)r0 - prc)) * (1.f - ((float)c1 - pcc));
    float grt = (1.f - ((float)r1 - prc)) * (1.f + ((float)c0 - pcc));

    int rr0 = r0 - 1, cc0 = c0 - 1, rr1 = r1 - 1, cc1 = c1 - 1;
    bool r0ok = (rr0 >= 0) && (rr0 < HH);
    bool r1ok = (rr1 >= 0) && (rr1 < HH);
    bool c0ok = (cc0 >= 0) && (cc0 < WW);
    bool c1ok = (cc1 >= 0) && (cc1 < WW);
    bool vlt = r0ok && c0ok, vrb = r1ok && c1ok;
    bool vlb = r0ok && c1ok, vrt = r1ok && c0ok;
    int o_lt = rr0 * WW + cc0, o_rb = rr1 * WW + cc1;
    int o_lb = rr0 * WW + cc1, o_rt = rr1 * WW + cc0;

    const float* xb = x + (size_t)b * IC * HH * WW;
#pragma unroll 4
    for (int it = 0; it < 16; ++it) {
        int c = it * 4 + cg;
        const float* xc = xb + (size_t)c * HH * WW;
        float v = 0.f;
        if (vlt) v += glt * xc[o_lt];
        if (vrb) v += grb * xc[o_rb];
        if (vlb) v += glb * xc[o_lb];
        if (vrt) v += grt * xc[o_rt];
        __hip_bfloat16 h = __float2bfloat16(v);
        ls[xl][c] = reinterpret_cast<unsigned short&>(h);
    }
    __syncthreads();

    // phase 2: c-fastest NHWC store (16 lanes cover one pixel's 64 ch)
    int c4 = (t & 15) << 2;    // channel granule base
    int xr = t >> 4;           // 0..15
    unsigned short* dst = xoff + (((size_t)bl * XOF + yy) * XPAD + xx0) * IC;
#pragma unroll
    for (int it2 = 0; it2 < 4; ++it2) {
        int xx2 = it2 * 16 + xr;
        const unsigned short* lp = &ls[xx2][c4];
        ushort4 v = { lp[0], lp[1], lp[2], lp[3] };
        *(ushort4*)(dst + (size_t)xx2 * IC + c4) = v;
    }
}

// ---------------------------------------------------------------------------
// Kernel C: bf16 MFMA implicit-GEMM conv. Block = 128 px (row segment) x
// 128 oc, 4 waves of 64x64, K = 576 in 18 steps of 32, double-buffered LDS,
// global_load_lds width 16, XCD-swizzled 1D grid.
// LDS A: [buf][cg:4][px:128][16B], LDS B: [buf][kg:4][oc:128][16B].
// ---------------------------------------------------------------------------
__global__ __launch_bounds__(256) void conv2_mfma(const unsigned short* __restrict__ xoff,
                                                  const unsigned short* __restrict__ Bt,
                                                  float* __restrict__ out,
                                                  int b0, int nwg) {
    __shared__ char lds[32768];

    // bijective XCD-chunk swizzle (m204)
    int orig = blockIdx.x;
    int q = nwg >> 3, r = nwg & 7;
    int xcd = orig & 7, loc = orig >> 3;
    int wgid = (xcd < r ? xcd * (q + 1) : r * (q + 1) + (xcd - r) * q) + loc;

    int xt  = wgid % 3;
    int tmp = wgid / 3;
    int oy  = tmp % OH2;
    int bl  = tmp / OH2;
    int x0  = xt << 7;

    int tid  = threadIdx.x;
    int wave = tid >> 6, lane = tid & 63;
    int wm = wave & 1, wn = wave >> 1;
    int lr = lane & 15, lc = lane >> 4;

    const char* xb = (const char*)xoff + (size_t)bl * ((size_t)XOF * XPAD * IC * 2);
    const char* bt = (const char*)Bt;

    f32x4 acc[4][4];
#pragma unroll
    for (int mf = 0; mf < 4; ++mf)
#pragma unroll
        for (int nf = 0; nf < 4; ++nf)
            acc[mf][nf] = (f32x4){0.f, 0.f, 0.f, 0.f};

    auto stage = [&](int buf, int s) {
        int kpos = s >> 1;
        int ky = kpos / 3, kx = kpos % 3;
        int icb = (s & 1) << 6;                       // byte offset of ic half
        const char* arow = xb + ((size_t)(oy + ky) * XPAD + (x0 + kx)) * (IC * 2) + icb;
        char* abase = lds + buf * 16384;
        char* bbase = abase + 8192;
        const char* bsrc = bt + (size_t)s * 8192;
#pragma unroll
        for (int qq = 0; qq < 2; ++qq) {
            int qa = wave * 2 + qq;
            int cg2 = qa >> 1;
            int px  = ((qa & 1) << 6) + lane;
            gload16(arow + (size_t)px * (IC * 2) + cg2 * 16, abase + qa * 1024);
            gload16(bsrc + ((size_t)qa * 64 + lane) * 16, bbase + qa * 1024);
        }
    };

    auto compute = [&](int buf) {
        const char* abase = lds + buf * 16384;
        const char* bbase = abase + 8192;
        bf16x8 af[4], bfr[4];
#pragma unroll
        for (int mf = 0; mf < 4; ++mf)
            af[mf] = *(const bf16x8*)(abase + lc * 2048 + (((wm << 6) + (mf << 4) + lr) << 4));
#pragma unroll
        for (int nf = 0; nf < 4; ++nf)
            bfr[nf] = *(const bf16x8*)(bbase + lc * 2048 + (((wn << 6) + (nf << 4) + lr) << 4));
#pragma unroll
        for (int mf = 0; mf < 4; ++mf)
#pragma unroll
            for (int nf = 0; nf < 4; ++nf)
                acc[mf][nf] = __builtin_amdgcn_mfma_f32_16x16x32_bf16(
                    af[mf], bfr[nf], acc[mf][nf], 0, 0, 0);
    };

    stage(0, 0);
    __syncthreads();
    int buf = 0;
    for (int s = 0; s < KSTEPS; ++s) {
        if (s + 1 < KSTEPS) stage(buf ^ 1, s + 1);
        compute(buf);
        __syncthreads();
        buf ^= 1;
    }

    int b = b0 + bl;
#pragma unroll
    for (int mf = 0; mf < 4; ++mf) {
        int ox0 = x0 + (wm << 6) + (mf << 4) + (lc << 2);
#pragma unroll
        for (int nf = 0; nf < 4; ++nf) {
            int oc = (wn << 6) + (nf << 4) + lr;
            float* po = out + (((size_t)b * OC + oc) * OH2 + oy) * OH2 + ox0;
            if (ox0 + 3 < OH2) {
                *(f32x4u*)po = acc[mf][nf];
            } else {
#pragma unroll
                for (int rr = 0; rr < 4; ++rr)
                    if (ox0 + rr < OH2) po[rr] = acc[mf][nf][rr];
            }
        }
    }
}

// ---------------------------------------------------------------------------
extern "C" void kernel_launch(void* const* d_in, const int* in_sizes, int n_in,
                              void* d_out, int out_size, void* d_ws, size_t ws_size,
                              hipStream_t stream) {
    const float* x      = (const float*)d_in[0];
    const float* w_p    = (const float*)d_in[1];
    const float* b_p    = (const float*)d_in[2];
    const float* w_conv = (const float*)d_in[3];
    float* out = (float*)d_out;

    const size_t offElems = (size_t)B_ * 18 * HH * WW;          // f32
    const size_t btElems  = (size_t)KSTEPS * 4 * 128 * 8;       // bf16
    const size_t xofElems = (size_t)XOF * XPAD * IC;            // bf16 per batch

    float* off = (float*)d_ws;
    unsigned short* Bt   = (unsigned short*)(off + offElems);
    unsigned short* xoff = Bt + btElems;

    const size_t headBytes = offElems * 4 + btElems * 2;
    const bool allBatch = ws_size >= headBytes + 4 * xofElems * 2;

    prep_w<<<(int)((btElems + 255) / 256), 256, 0, stream>>>(w_conv, Bt);
    offset_conv<<<(B_ * HH * WW) / 256, 256, 0, stream>>>(x, w_p, b_p, off);

    if (allBatch) {
        pad_zero<<<B_ * XOF, 256, 0, stream>>>(xoff, B_);
        dim3 sg(XOF / 64, XOF, B_);
        sample_nhwc<<<sg, 256, 0, stream>>>(x, off, xoff, 0, B_);
        int nwg = B_ * 3 * OH2;
        conv2_mfma<<<nwg, 256, 0, stream>>>(xoff, Bt, out, 0, nwg);
    } else {
        pad_zero<<<XOF, 256, 0, stream>>>(xoff, 1);
        for (int b = 0; b < B_; ++b) {
            dim3 sg(XOF / 64, XOF, 1);
            sample_nhwc<<<sg, 256, 0, stream>>>(x, off, xoff, b, 1);
            int nwg = 3 * OH2;
            conv2_mfma<<<nwg, 256, 0, stream>>>(xoff, Bt, out, b, nwg);
        }
    }
}

// Round 3
// 383.318 us; speedup vs baseline: 4.0904x; 1.0329x over previous
//
#include <hip/hip_runtime.h>
#include <hip/hip_bf16.h>

#define B_   4
#define IC   64
#define OC   128
#define HH   128
#define WW   128
#define HP   130      // padded H/W for sampling
#define XOF  384      // x_off spatial (128*3)
#define XPAD 388      // padded x-dim of granule layout
#define OH2  382      // final output spatial
#define KSTEPS 18     // 9 kernel positions * 2 ic-halves (K=32 each)

typedef __attribute__((ext_vector_type(4))) float f32x4;
typedef __attribute__((ext_vector_type(8))) __bf16 bf16x8;
typedef __attribute__((ext_vector_type(8))) unsigned short us8;
typedef __attribute__((ext_vector_type(4), aligned(4))) float f32x4u;

__device__ __forceinline__ void gload16(const void* gsrc, void* ldst) {
    __builtin_amdgcn_global_load_lds(
        (const __attribute__((address_space(1))) void*)gsrc,
        (__attribute__((address_space(3))) void*)ldst, 16, 0, 0);
}

// ---------------------------------------------------------------------------
// Kernel A1: offset conv partials. Block = 16x16 px tile, z = b*2 + ic-half.
// LDS-staged x tile (8 ic x 18 x 18), each thread accumulates 18 channels
// over its 32-ic half. part[z][co][py][px].
// ---------------------------------------------------------------------------
#define ICH 32
#define ICS 8
__global__ __launch_bounds__(256) void offset_part(const float* __restrict__ x,
                                                   const float* __restrict__ w_p,
                                                   float* __restrict__ part) {
    __shared__ float sx[ICS][18][18];

    int tx0 = blockIdx.x * 16;
    int ty0 = blockIdx.y * 16;
    int z   = blockIdx.z;
    int b   = z >> 1;
    int ic0 = (z & 1) * ICH;

    int tid = threadIdx.x;
    int lx  = tid & 15;
    int ly  = tid >> 4;

    float acc[18];
#pragma unroll
    for (int co = 0; co < 18; ++co) acc[co] = 0.f;

    const float* xb = x + ((size_t)b * IC + ic0) * HH * WW;

    for (int c0 = 0; c0 < ICH; c0 += ICS) {
        __syncthreads();
        for (int idx = tid; idx < ICS * 18 * 18; idx += 256) {
            int col = idx % 18;
            int row = (idx / 18) % 18;
            int ic  = idx / 324;
            int gy = ty0 + row - 1, gx = tx0 + col - 1;
            bool ok = (gy >= 0) && (gy < HH) && (gx >= 0) && (gx < WW);
            int cy = min(max(gy, 0), HH - 1);
            int cx = min(max(gx, 0), WW - 1);
            float v = xb[((size_t)(c0 + ic)) * HH * WW + cy * WW + cx];
            sx[ic][row][col] = ok ? v : 0.f;
        }
        __syncthreads();

#pragma unroll
        for (int ic = 0; ic < ICS; ++ic) {
            float xv[9];
#pragma unroll
            for (int ky = 0; ky < 3; ++ky)
#pragma unroll
                for (int kx = 0; kx < 3; ++kx)
                    xv[ky * 3 + kx] = sx[ic][ly + ky][lx + kx];
#pragma unroll
            for (int co = 0; co < 18; ++co) {
                const float* wrow = w_p + ((size_t)co * IC + ic0 + c0 + ic) * 9;
#pragma unroll
                for (int k = 0; k < 9; ++k)
                    acc[co] = fmaf(wrow[k], xv[k], acc[co]);
            }
        }
    }

    float* pp = part + (size_t)z * 18 * HH * WW + (size_t)(ty0 + ly) * WW + tx0 + lx;
#pragma unroll
    for (int co = 0; co < 18; ++co) pp[(size_t)co * HH * WW] = acc[co];
}

// ---------------------------------------------------------------------------
// Kernel A2: merge partials + bias -> off[b][co][py][px]
// ---------------------------------------------------------------------------
__global__ __launch_bounds__(256) void merge_off(const float* __restrict__ part,
                                                 const float* __restrict__ b_p,
                                                 float* __restrict__ off) {
    const int S = 18 * HH * WW;
    int t = blockIdx.x * 256 + threadIdx.x;        // 4*S exact
    int b = t / S;
    int rem = t - b * S;
    int co = rem >> 14;
    off[t] = part[(size_t)(b * 2) * S + rem] + part[(size_t)(b * 2 + 1) * S + rem] + b_p[co];
}

// ---------------------------------------------------------------------------
// Kernel P: weights -> bf16 K-step tiles Bt[s][kg:4][oc:128][e:8]
// ic = (s&1)*32 + kg*8 + e ; kpos = s>>1
// ---------------------------------------------------------------------------
__global__ __launch_bounds__(256) void prep_w(const float* __restrict__ wc,
                                              unsigned short* __restrict__ Bt) {
    int t = blockIdx.x * 256 + threadIdx.x;
    if (t >= KSTEPS * 4 * 128 * 8) return;
    int e  = t & 7;
    int oc = (t >> 3) & 127;
    int kg = (t >> 10) & 3;
    int s  = t >> 12;
    int ic = ((s & 1) << 5) + (kg << 3) + e;
    int kpos = s >> 1;
    int ky = kpos / 3, kx = kpos % 3;
    float v = wc[(((size_t)oc * IC + ic) * 3 + ky) * 3 + kx];
    __hip_bfloat16 h = __float2bfloat16(v);
    Bt[t] = reinterpret_cast<unsigned short&>(h);
}

// ---------------------------------------------------------------------------
// Kernel Z: zero pad columns x in [384,388) of granule-layout x_off.
// One thread per 16B granule-slot: nb*384*8*4 threads.
// ---------------------------------------------------------------------------
__global__ __launch_bounds__(256) void pad_zero_g(unsigned short* __restrict__ xoff, int nb) {
    int t = blockIdx.x * 256 + threadIdx.x;
    int xp = t & 3;
    int cg = (t >> 2) & 7;
    int rest = t >> 5;
    int yy = rest % XOF;
    int bl = rest / XOF;
    if (bl >= nb) return;
    size_t di = ((((size_t)bl * XOF + yy) * 8 + cg) * XPAD + XOF + xp) * 8;
    us8 z = (us8)0;
    *(us8*)(xoff + di) = z;
}

// ---------------------------------------------------------------------------
// Kernel B: bilinear sampling -> bf16 granule layout xoff[bl][yy][cg][x][8].
// Thread = (pixel, granule): 256 thr = 32 px x 8 cg. Coeffs computed per
// thread, 8-channel branchless gather, one 16B store. XCD-chunked grid so
// each XCD's L2 sees ~half a batch of x. Sampling math identical to R1/R2.
// ---------------------------------------------------------------------------
__global__ __launch_bounds__(256) void sample_g(const float* __restrict__ x,
                                                const float* __restrict__ off,
                                                unsigned short* __restrict__ xoff,
                                                int b0, int nwg) {
    int orig = blockIdx.x;
    int chunk = nwg >> 3;                    // nwg divisible by 8
    int wg = (orig & 7) * chunk + (orig >> 3);

    int xt  = wg % 12;
    int tmp = wg / 12;
    int yy  = tmp % XOF;
    int bl  = tmp / XOF;
    int b   = b0 + bl;
    int xx0 = xt * 32;

    int t  = threadIdx.x;
    int xl = t & 31;
    int cg = t >> 5;
    int xx = xx0 + xl;

    int j = xx / 3, kw = xx % 3;
    int i = yy / 3, kh = yy % 3;
    int n = kh * 3 + kw;

    const float* offb = off + (size_t)b * 18 * HH * WW + (size_t)i * WW + j;
    float offr = offb[(size_t)n * HH * WW];
    float offc = offb[(size_t)(n + 9) * HH * WW];

    float pr = (float)(i + kh) + offr;
    float pc = (float)(j + kw) + offc;

    float r0f = floorf(pr), c0f = floorf(pc);
    int r0 = min(max((int)r0f, 0), HP - 1);
    int c0 = min(max((int)c0f, 0), HP - 1);
    int r1 = min(max((int)(r0f + 1.f), 0), HP - 1);
    int c1 = min(max((int)(c0f + 1.f), 0), HP - 1);

    float prc = fminf(fmaxf(pr, 0.f), (float)(HP - 1));
    float pcc = fminf(fmaxf(pc, 0.f), (float)(HP - 1));

    float glt = (1.f + ((float)r0 - prc)) * (1.f + ((float)c0 - pcc));
    float grb = (1.f - ((float)r1 - prc)) * (1.f - ((float)c1 - pcc));
    float glb = (1.f + ((float)r0 - prc)) * (1.f - ((float)c1 - pcc));
    float grt = (1.f - ((float)r1 - prc)) * (1.f + ((float)c0 - pcc));

    int rr0 = r0 - 1, cc0 = c0 - 1, rr1 = r1 - 1, cc1 = c1 - 1;
    bool r0ok = (rr0 >= 0) && (rr0 < HH);
    bool r1ok = (rr1 >= 0) && (rr1 < HH);
    bool c0ok = (cc0 >= 0) && (cc0 < WW);
    bool c1ok = (cc1 >= 0) && (cc1 < WW);

    float wlt = (r0ok && c0ok) ? glt : 0.f;
    float wrb = (r1ok && c1ok) ? grb : 0.f;
    float wlb = (r0ok && c1ok) ? glb : 0.f;
    float wrt = (r1ok && c0ok) ? grt : 0.f;
    int olt = (r0ok && c0ok) ? (rr0 * WW + cc0) : 0;
    int orb = (r1ok && c1ok) ? (rr1 * WW + cc1) : 0;
    int olb = (r0ok && c1ok) ? (rr0 * WW + cc1) : 0;
    int ort = (r1ok && c0ok) ? (rr1 * WW + cc0) : 0;

    const float* xg = x + ((size_t)b * IC + cg * 8) * HH * WW;

    us8 res;
#pragma unroll
    for (int e = 0; e < 8; ++e) {
        const float* xc = xg + (size_t)e * HH * WW;
        float v = wlt * xc[olt] + wrb * xc[orb] + wlb * xc[olb] + wrt * xc[ort];
        __hip_bfloat16 h = __float2bfloat16(v);
        res[e] = reinterpret_cast<unsigned short&>(h);
    }

    size_t di = ((((size_t)bl * XOF + yy) * 8 + cg) * XPAD + xx) * 8;
    *(us8*)(xoff + di) = res;
}

// ---------------------------------------------------------------------------
// Kernel C: bf16 MFMA implicit-GEMM conv. Block = 2 output rows x 128 px x
// 128 oc, 8 waves (512 thr), each wave 64 M x 64 oc. K = 576, 18 steps of 32.
// Double-buffered LDS (48 KB), all staging via contiguous 1 KB global_load_lds.
// LDS A: [row:2][cg:4][px:128][16B], LDS B: [kg:4][oc:128][16B].
// ---------------------------------------------------------------------------
__global__ __launch_bounds__(512) void conv2_mfma(const unsigned short* __restrict__ xoff,
                                                  const unsigned short* __restrict__ Bt,
                                                  float* __restrict__ out,
                                                  int b0, int nwg) {
    __shared__ __align__(16) char lds[49152];

    // bijective XCD-chunk swizzle (m204)
    int orig = blockIdx.x;
    int q = nwg >> 3, r = nwg & 7;
    int xcd = orig & 7, loc = orig >> 3;
    int wgid = (xcd < r ? xcd * (q + 1) : r * (q + 1) + (xcd - r) * q) + loc;

    int xt  = wgid % 3;
    int tmp = wgid / 3;
    int yp  = tmp % 191;
    int bl  = tmp / 191;
    int oy  = yp * 2;
    int x0  = xt << 7;

    int tid  = threadIdx.x;
    int wave = tid >> 6, lane = tid & 63;
    int wm = wave >> 1;            // 0..3 -> (row = wm>>1, px-half = wm&1)
    int wn = wave & 1;             // oc half
    int rowsel = wm >> 1, pxh = wm & 1;
    int lr = lane & 15, lc = lane >> 4;

    const char* xb = (const char*)xoff + (size_t)bl * ((size_t)XOF * 8 * XPAD * 16);
    const char* bt = (const char*)Bt;

    f32x4 acc[4][4];
#pragma unroll
    for (int mf = 0; mf < 4; ++mf)
#pragma unroll
        for (int nf = 0; nf < 4; ++nf)
            acc[mf][nf] = (f32x4){0.f, 0.f, 0.f, 0.f};

    auto stage = [&](int buf, int s) {
        int kpos = s >> 1;
        int ky = kpos / 3, kx = kpos % 3;
        int icg = (s & 1) << 2;                    // granule base 0 / 4
        char* abase = lds + buf * 24576;
        char* bbase = abase + 16384;
        const char* bsrc = bt + (size_t)s * 8192;
#pragma unroll
        for (int qq = 0; qq < 3; ++qq) {
            int qa = wave * 3 + qq;                // 0..23, wave-uniform
            if (qa < 16) {
                int rr  = qa >> 3;
                int cgp = (qa >> 1) & 3;
                int ph  = qa & 1;
                const char* src = xb +
                    ((((size_t)(oy + rr + ky)) * 8 + icg + cgp) * XPAD + x0 + kx + ph * 64 + lane) * 16;
                char* dst = abase + (((rr * 4 + cgp) * 128) + ph * 64 + lane) * 16;
                gload16(src, dst);
            } else {
                int g = qa - 16;
                gload16(bsrc + (size_t)(g * 64 + lane) * 16,
                        bbase + (g * 64 + lane) * 16);
            }
        }
    };

    auto compute = [&](int buf) {
        const char* abase = lds + buf * 24576;
        const char* bbase = abase + 16384;
        bf16x8 af[4], bfr[4];
#pragma unroll
        for (int mf = 0; mf < 4; ++mf)
            af[mf] = *(const bf16x8*)(abase +
                (((rowsel * 4 + lc) * 128) + pxh * 64 + mf * 16 + lr) * 16);
#pragma unroll
        for (int nf = 0; nf < 4; ++nf)
            bfr[nf] = *(const bf16x8*)(bbase +
                ((lc * 128) + wn * 64 + nf * 16 + lr) * 16);
#pragma unroll
        for (int mf = 0; mf < 4; ++mf)
#pragma unroll
            for (int nf = 0; nf < 4; ++nf)
                acc[mf][nf] = __builtin_amdgcn_mfma_f32_16x16x32_bf16(
                    af[mf], bfr[nf], acc[mf][nf], 0, 0, 0);
    };

    stage(0, 0);
    __syncthreads();
    int buf = 0;
    for (int s = 0; s < KSTEPS; ++s) {
        if (s + 1 < KSTEPS) stage(buf ^ 1, s + 1);
        compute(buf);
        __syncthreads();
        buf ^= 1;
    }

    int b = b0 + bl;
    int orow = oy + rowsel;
#pragma unroll
    for (int mf = 0; mf < 4; ++mf) {
        int ox0 = x0 + pxh * 64 + mf * 16 + (lc << 2);
#pragma unroll
        for (int nf = 0; nf < 4; ++nf) {
            int oc = wn * 64 + nf * 16 + lr;
            float* po = out + (((size_t)b * OC + oc) * OH2 + orow) * OH2 + ox0;
            if (ox0 + 3 < OH2) {
                *(f32x4u*)po = acc[mf][nf];
            } else {
#pragma unroll
                for (int rr = 0; rr < 4; ++rr)
                    if (ox0 + rr < OH2) po[rr] = acc[mf][nf][rr];
            }
        }
    }
}

// ---------------------------------------------------------------------------
extern "C" void kernel_launch(void* const* d_in, const int* in_sizes, int n_in,
                              void* d_out, int out_size, void* d_ws, size_t ws_size,
                              hipStream_t stream) {
    const float* x      = (const float*)d_in[0];
    const float* w_p    = (const float*)d_in[1];
    const float* b_p    = (const float*)d_in[2];
    const float* w_conv = (const float*)d_in[3];
    float* out = (float*)d_out;

    const size_t offElems  = (size_t)B_ * 18 * HH * WW;         // f32
    const size_t partElems = 2 * offElems;                      // f32
    const size_t btElems   = (size_t)KSTEPS * 4 * 128 * 8;      // bf16
    const size_t xofElems  = (size_t)XOF * 8 * XPAD * 8;        // bf16 per batch

    float* off  = (float*)d_ws;
    float* part = off + offElems;
    unsigned short* Bt   = (unsigned short*)(part + partElems);
    unsigned short* xoff = Bt + btElems;

    const size_t headBytes = (offElems + partElems) * 4 + btElems * 2;
    const bool allBatch = ws_size >= headBytes + 4 * xofElems * 2;

    prep_w<<<(int)((btElems + 255) / 256), 256, 0, stream>>>(w_conv, Bt);

    dim3 og(8, 8, B_ * 2);
    offset_part<<<og, 256, 0, stream>>>(x, w_p, part);
    merge_off<<<(int)(offElems / 256), 256, 0, stream>>>(part, b_p, off);

    if (allBatch) {
        pad_zero_g<<<B_ * 48, 256, 0, stream>>>(xoff, B_);
        int snwg = 12 * XOF * B_;                 // 18432
        sample_g<<<snwg, 256, 0, stream>>>(x, off, xoff, 0, snwg);
        int cnwg = 3 * 191 * B_;                  // 2292
        conv2_mfma<<<cnwg, 512, 0, stream>>>(xoff, Bt, out, 0, cnwg);
    } else {
        for (int b = 0; b < B_; ++b) {
            pad_zero_g<<<48, 256, 0, stream>>>(xoff, 1);
            int snwg = 12 * XOF;                  // 4608
            sample_g<<<snwg, 256, 0, stream>>>(x, off, xoff, b, snwg);
            int cnwg = 3 * 191;                   // 573
            conv2_mfma<<<cnwg, 512, 0, stream>>>(xoff, Bt, out, b, cnwg);
        }
    }
}